// Round 7
// baseline (147.163 us; speedup 1.0000x reference)
//
#include <hip/hip_runtime.h>
#include <stdint.h>

#define IH 4096
#define IW 4096
#define OH 4090
#define OW 4090

#define TW 256                 // output tile width (block column strip)
#define STEP 24                // output rows per step
#define WIN 30                 // input rows per window (STEP+6)
#define LW 272                 // LDS row stride in floats (= NV4*4, rows butt together)
#define NV4 68                 // float4 per LDS row
#define NLD (WIN * NV4)        // 2040 float4 per window stage
#define NSTEPS 11              // steps per block
#define BROWS (STEP * NSTEPS)  // 264 output rows per block

typedef float v2f __attribute__((ext_vector_type(2)));
typedef __attribute__((address_space(1))) void gas_void;
typedef __attribute__((address_space(3))) void las_void;

// Law from R1-R6 counters: dur ~= blocksPerCU * blockLatency (HW runs ~1 block/CU
// at VGPR>=100; occupancy never >20%). So: grid = 256 blocks = exactly 1/CU, and
// ALL latency-hiding waves live inside the block (1024 thr = 16 waves = 4/SIMD).
// Double-buffered global_load_lds staging (R6's proven overlap structure).
__device__ __forceinline__ void stage_tile(const float* __restrict__ x,
                                           int y0, int x0, float* sbuf,
                                           int tid, int wv)
{
#pragma unroll
    for (int i = 0; i < 2; ++i) {
        const int f = tid + i * 1024;
        if (f < NLD) {
            const int r  = f / NV4;                 // magic-mul
            const int c4 = f - r * NV4;
            int iy = y0 + r;
            iy = iy < IH ? iy : IH - 1;             // y clamp: feeds only unstored rows
            int c0 = x0 + 4 * c4;
            c0 = c0 <= IW - 4 ? c0 : IW - 4;        // x clamp: keep 16B in-bounds
            const float* gp = x + (size_t)iy * IW + c0;
            // LDS dest must be wave-uniform base + lane*16 (m104/m108): flat-f
            // layout is lane-contiguous because NV4*16B == LW*4B.
            float* lp = sbuf + (size_t)(i * 1024 + wv * 64) * 4;
            __builtin_amdgcn_global_load_lds((gas_void*)gp, (las_void*)lp, 16, 0, 0);
        }
    }
}

__global__ __launch_bounds__(1024) void conv7x7_kernel(
    const float* __restrict__ x,
    const float* __restrict__ w,
    const float* __restrict__ bias,
    float* __restrict__ out)
{
    __shared__ float smem[2][WIN * LW];             // 2 x 32,640 B = 65,280 B

    const int tid = threadIdx.x;
    const int wv  = tid >> 6;
    const int txx = tid & 127;                      // 0..127 -> 2-wide columns
    const int tyy = tid >> 7;                       // 0..7   -> 3-tall bands
    const int x0  = blockIdx.x * TW;
    const int yb  = blockIdx.y * BROWS;             // block's first output row

    // Wave-uniform weights -> SGPRs.
    float wt[49];
#pragma unroll
    for (int k = 0; k < 49; ++k) wt[k] = w[k];
    const float b = bias[0];

    stage_tile(x, yb, x0, smem[0], tid, wv);

    const int ox0 = x0 + 2 * txx;                   // even -> 8B-aligned stores

    for (int s = 0; s < NSTEPS; ++s) {
        __syncthreads();                            // own-wave vmcnt(0) + barrier: buf[s&1] ready
        if (s + 1 < NSTEPS)
            stage_tile(x, yb + (s + 1) * STEP, x0, smem[(s + 1) & 1], tid, wv);

        const float* sb = smem[s & 1];

        float acc[3][2];
#pragma unroll
        for (int r = 0; r < 3; ++r) { acc[r][0] = b; acc[r][1] = b; }

#pragma unroll
        for (int ir = 0; ir < 9; ++ir) {            // 9 input rows feed 3 output rows
            const float* srow = sb + (3 * tyy + ir) * LW + 2 * txx;
            float rb[8];                            // 4x float2, 8B lane stride: 2-way alias = free
            const float2 p0 = *(const float2*)(srow);
            const float2 p1 = *(const float2*)(srow + 2);
            const float2 p2 = *(const float2*)(srow + 4);
            const float2 p3 = *(const float2*)(srow + 6);
            rb[0]=p0.x; rb[1]=p0.y; rb[2]=p1.x; rb[3]=p1.y;
            rb[4]=p2.x; rb[5]=p2.y; rb[6]=p3.x; rb[7]=p3.y;

#pragma unroll
            for (int ky = 0; ky < 7; ++ky) {
                const int ry = ir - ky;             // folded at compile time
                if (ry >= 0 && ry < 3) {
#pragma unroll
                    for (int kx = 0; kx < 7; ++kx) {
                        const float wv_ = wt[ky * 7 + kx];
                        acc[ry][0] += wv_ * rb[kx];
                        acc[ry][1] += wv_ * rb[kx + 1];
                    }
                }
            }
        }

        // Stores: ox0 and OW both even -> ox0 < OW implies ox0+1 < OW (no scalar path).
        const int oyb = yb + s * STEP + 3 * tyy;
#pragma unroll
        for (int ry = 0; ry < 3; ++ry) {
            const int oy = oyb + ry;
            if (oy < OH && ox0 < OW) {
                v2f v = { acc[ry][0], acc[ry][1] };
                __builtin_nontemporal_store(v, (v2f*)(out + (size_t)oy * OW + ox0));
            }
        }
    }
}

extern "C" void kernel_launch(void* const* d_in, const int* in_sizes, int n_in,
                              void* d_out, int out_size, void* d_ws, size_t ws_size,
                              hipStream_t stream) {
    const float* x    = (const float*)d_in[0];
    const float* w    = (const float*)d_in[1];
    const float* bias = (const float*)d_in[2];
    float* out        = (float*)d_out;

    // 16 x-strips x 16 y-groups = 256 blocks = exactly 1 per CU.
    // y coverage: 16 * 264 = 4224 >= 4090 (last group ~3% wasted, clamped+guarded).
    dim3 grid(16, 16);
    conv7x7_kernel<<<grid, dim3(1024), 0, stream>>>(x, w, bias, out);
}